// Round 13
// baseline (377.388 us; speedup 1.0000x reference)
//
#include <hip/hip_runtime.h>

// N=2, T=S=1024, B=4, E=1024, H=16, HD=64
// d_in: query[T,B,E], keys[N,S,B,E], masks[N,B,S](int), Wq[N,E,E], bq[N,E],
//       Wk[N,E,E], bk[N,E], Wv[N,E,E], bv[N,E], Wo[E,E], bo[E]  (all fp32)

typedef __bf16 bf16x8 __attribute__((ext_vector_type(8)));
typedef unsigned short u16x8 __attribute__((ext_vector_type(8)));
typedef unsigned short u16x4 __attribute__((ext_vector_type(4)));
typedef float f32x4 __attribute__((ext_vector_type(4)));

// ws layout (ushort element offsets); total 47M elements = 94 MB
#define OFF_QP 0ul            // [N*B*H][1024 t][64 d] bf16 q (pre-scaled 0.125)
#define OFF_KP (8ul << 20)    // [N*B*H][1024 s][64 d] bf16 k
#define OFF_VP (16ul << 20)   // [N*B*H][64 d][1024 s] bf16 v  (d-major!)
#define OFF_AO (24ul << 20)   // [4096][1024] bf16 attention output
#define OFF_XQ (28ul << 20)   // query bf16 [4096][1024]
#define OFF_XK (32ul << 20)   // keys bf16 [2][4096][1024]
#define OFF_W (40ul << 20)    // Wq(2M) Wk(2M) Wv(2M) bf16
#define OFF_WO (46ul << 20)   // Wo bf16 (1M)

__device__ __forceinline__ unsigned short f2bf(float x) {
  unsigned u = __builtin_bit_cast(unsigned, x);
  return (unsigned short)((u + 0x7fffu + ((u >> 16) & 1u)) >> 16);
}
__device__ __forceinline__ float bf2f(unsigned short h) {
  return __builtin_bit_cast(float, (unsigned)h << 16);
}
__device__ __forceinline__ void gload16(const void* g, void* l) {
  __builtin_amdgcn_global_load_lds(
      (const __attribute__((address_space(1))) unsigned*)g,
      (__attribute__((address_space(3))) unsigned*)l, 16, 0, 0);
}

// ---------------------------------------------------------------------------
// fp32 -> bf16 conversions, one launch, blockIdx.y picks region
// ---------------------------------------------------------------------------
__global__ __launch_bounds__(256) void cvt_all(
    const float* __restrict__ q, const float* __restrict__ k,
    const float* __restrict__ wq, const float* __restrict__ wk,
    const float* __restrict__ wv, const float* __restrict__ wo,
    unsigned short* __restrict__ ws) {
  const int z = blockIdx.y;
  const float* src;
  unsigned short* dst;
  unsigned nq;  // float4 count
  if (z == 0)      { src = q;  dst = ws + OFF_XQ;              nq = 1u << 20; }
  else if (z == 1) { src = k;  dst = ws + OFF_XK;              nq = 2u << 20; }
  else if (z == 2) { src = wq; dst = ws + OFF_W;               nq = 1u << 19; }
  else if (z == 3) { src = wk; dst = ws + OFF_W + (2ul << 20); nq = 1u << 19; }
  else if (z == 4) { src = wv; dst = ws + OFF_W + (4ul << 20); nq = 1u << 19; }
  else             { src = wo; dst = ws + OFF_WO;              nq = 1u << 18; }
  for (unsigned i = blockIdx.x * 256 + threadIdx.x; i < nq; i += gridDim.x * 256) {
    float4 v = ((const float4*)src)[i];
    u16x4 o = {f2bf(v.x), f2bf(v.y), f2bf(v.z), f2bf(v.w)};
    *(u16x4*)&dst[(size_t)i * 4] = o;
  }
}

// ---------------------------------------------------------------------------
// bf16 MFMA GEMM with T4 counted-vmcnt pipeline: 4 LDS buffers, staging depth
// 2, ONE raw s_barrier per K-step, s_waitcnt vmcnt(8) (never 0 mid-loop) so
// 8 global_load_lds stay in flight across barriers. 128x128 tile, BK=32,
// 4 waves (2x2), 4x4 frags of 16x16x32.
// Hazards: RAW via per-wave vmcnt + barrier; WAR: buf[(t+2)&3] last read at
// iter t-2, whose reads completed (lgkmcnt(0) pre-MFMA) before barrier t-1.
// mode 0: bf16 scatter [nbh][seq][64]; mode 1: bf16 d-major [nbh][64][1024];
// mode 2: fp32 row-major.
// ---------------------------------------------------------------------------
__device__ __forceinline__ void gemm_mfma(const unsigned short* __restrict__ A,
                                          const unsigned short* __restrict__ B,
                                          const float* __restrict__ bias,
                                          void* __restrict__ outp, int nsrc,
                                          float scale, int mode) {
  __shared__ unsigned short As[4][4096];  // [buf][4 k-octet slabs][128 rows][8]
  __shared__ unsigned short Bs[4][4096];
  const int tid = threadIdx.x;
  const int w = tid >> 6, lane = tid & 63;
  const int wr = w >> 1, wc = w & 1;
  const long row0 = (long)blockIdx.x * 128, col0 = (long)blockIdx.y * 128;

  f32x4 acc[4][4] = {};

  const unsigned short* ga0 = A + (row0 + lane) * 1024 + w * 8;
  const unsigned short* ga1 = ga0 + 64 * 1024;
  const unsigned short* gb0 = B + (col0 + lane) * 1024 + w * 8;
  const unsigned short* gb1 = gb0 + 64 * 1024;

  const int kb = (lane >> 4) * 1024;
  const int fr = lane & 15;

  auto stage = [&](int buf, int k0) {
    gload16(ga0 + k0, &As[buf][w * 1024]);
    gload16(ga1 + k0, &As[buf][w * 1024 + 512]);
    gload16(gb0 + k0, &Bs[buf][w * 1024]);
    gload16(gb1 + k0, &Bs[buf][w * 1024 + 512]);
  };

  // prologue: tiles 0 and 1 in flight (8 loads)
  stage(0, 0);
  stage(1, 32);

  for (int k0 = 0; k0 < 1024; k0 += 32) {
    const int t = k0 >> 5;
    if (k0 + 64 < 1024) {
      stage((t + 2) & 3, k0 + 64);  // depth-2 prefetch, stays in flight
      asm volatile("s_waitcnt vmcnt(8)" ::: "memory");  // tile t landed (FIFO)
    } else if (k0 + 32 < 1024) {
      asm volatile("s_waitcnt vmcnt(4)" ::: "memory");
    } else {
      asm volatile("s_waitcnt vmcnt(0)" ::: "memory");
    }
    __builtin_amdgcn_s_barrier();        // all waves' tile-t loads landed
    __builtin_amdgcn_sched_barrier(0);   // pin ds_reads below the barrier

    const unsigned short* as = As[t & 3];
    const unsigned short* bs = Bs[t & 3];
    bf16x8 af[4], bfr[4];
#pragma unroll
    for (int m = 0; m < 4; ++m)
      af[m] = __builtin_bit_cast(
          bf16x8, *(const u16x8*)&as[kb + (wr * 64 + m * 16 + fr) * 8]);
#pragma unroll
    for (int nn = 0; nn < 4; ++nn)
      bfr[nn] = __builtin_bit_cast(
          bf16x8, *(const u16x8*)&bs[kb + (wc * 64 + nn * 16 + fr) * 8]);
    asm volatile("s_waitcnt lgkmcnt(0)" ::: "memory");  // reads done pre-MFMA
    __builtin_amdgcn_sched_barrier(0);   // rule 18: MFMA must not hoist above
#pragma unroll
    for (int m = 0; m < 4; ++m)
#pragma unroll
      for (int nn = 0; nn < 4; ++nn)
        acc[m][nn] = __builtin_amdgcn_mfma_f32_16x16x32_bf16(af[m], bfr[nn],
                                                             acc[m][nn], 0, 0, 0);
  }

  const int fq = lane >> 4;
#pragma unroll
  for (int m = 0; m < 4; ++m)
#pragma unroll
    for (int nn = 0; nn < 4; ++nn) {
      const long col = col0 + wc * 64 + nn * 16 + fr;
      const float bcol = bias[col];
#pragma unroll
      for (int r = 0; r < 4; ++r) {
        const long row = row0 + wr * 64 + m * 16 + fq * 4 + r;
        const float v = (acc[m][nn][r] + bcol) * scale;
        const long t = row >> 2, bb = row & 3;  // row = t*4 + b
        const long h = col >> 6, d = col & 63;  // col = h*64 + d
        const long nbh = ((long)nsrc * 4 + bb) * 16 + h;
        if (mode == 2)
          ((float*)outp)[row * 1024 + col] = v;
        else if (mode == 0)
          ((unsigned short*)outp)[(nbh * 1024 + t) * 64 + d] = f2bf(v);
        else
          ((unsigned short*)outp)[nbh * 65536 + d * 1024 + t] = f2bf(v);
      }
    }
}

// fused q/k/v projections, blockIdx.z = type*2 + n
__global__ __launch_bounds__(256) void proj_fused(unsigned short* __restrict__ ws,
                                                  const float* __restrict__ bq,
                                                  const float* __restrict__ bk,
                                                  const float* __restrict__ bv) {
  const int z = blockIdx.z;
  const int n = z & 1, type = z >> 1;
  const unsigned short* A =
      ws + (type == 0 ? OFF_XQ : OFF_XK + (unsigned long)n * (4ul << 20));
  const unsigned short* B = ws + OFF_W + (unsigned long)(type * 2 + n) * (1ul << 20);
  const float* bias = ((type == 0) ? bq : (type == 1) ? bk : bv) + n * 1024;
  unsigned short* out = ws + (type == 0 ? OFF_QP : (type == 1) ? OFF_KP : OFF_VP);
  const float scale = (type == 0) ? 0.125f : 1.0f;
  gemm_mfma(A, B, bias, out, n, scale, (type == 2) ? 1 : 0);
}

__global__ __launch_bounds__(256) void gemm_out(const unsigned short* __restrict__ ws_c,
                                                const float* __restrict__ bias,
                                                float* __restrict__ out) {
  gemm_mfma(ws_c + OFF_AO, ws_c + OFF_WO, bias, (void*)out, 0, 1.0f, 2);
}

// ---------------------------------------------------------------------------
// MFMA flash attention + T14 async-STAGE split (unchanged from r12 pass).
// Block 256 = 4 waves; wave owns 16 q-rows. Grid (16, H, B).
//   S^T = mfma(A=K, B=Q^T); row stats via 2 shfl; P->bf16->per-wave LDS;
//   O^T += mfma(A=V^T, B=P^T)  (V staged d-major).
// qp/kp: [nbh][seq][64]; vpt: [nbh][64][1024]; masks int[N,B,S] nonzero=pad.
// ao: bf16 [t*4+b][h*64+d]
// ---------------------------------------------------------------------------
__global__ __launch_bounds__(256) void attn_mfma(
    const unsigned short* __restrict__ qp, const unsigned short* __restrict__ kp,
    const unsigned short* __restrict__ vpt, const int* __restrict__ masks,
    unsigned short* __restrict__ ao) {
  __shared__ __align__(16) unsigned short Ks[64 * 72];   // [key][72]
  __shared__ __align__(16) unsigned short Vt[64 * 72];   // [d][72]
  __shared__ __align__(16) unsigned short Pl[4 * 16 * 72];  // per-wave [q][72]
  __shared__ __align__(16) float mba[2 * 1024];          // -3e38 / 0 per key

  const int tid = threadIdx.x;
  const int w = tid >> 6, l = tid & 63;
  const int g = l >> 4, q16 = l & 15;
  const int b = blockIdx.z, h = blockIdx.y;
  const int t0 = blockIdx.x * 64 + w * 16;

  // stage masks for both sources as f32 add-terms
#pragma unroll
  for (int p = 0; p < 2; ++p) {
    const int idx = tid + p * 256;            // 0..511
    const int n = idx >> 8, off = (idx & 255) * 4;
    const int4 mi = *(const int4*)&masks[((long)n * 4 + b) * 1024 + off];
    f32x4 mf = {mi.x ? -3.0e38f : 0.0f, mi.y ? -3.0e38f : 0.0f,
                mi.z ? -3.0e38f : 0.0f, mi.w ? -3.0e38f : 0.0f};
    *(f32x4*)&mba[n * 1024 + off] = mf;
  }

  float m = -3.0e38f, ls = 0.0f;
  f32x4 o[4] = {};  // O^T d-frags: d = df*16 + g*4 + r, col = qrow

  unsigned short* pw = &Pl[(w * 16 + q16) * 72];

  // T14 prefetch registers: this thread's 2 K-chunks + 2 V-chunks (16B each)
  const int r8 = tid >> 3, c8 = (tid & 7) * 8;  // chunk tid: row r8 / r8+32
  u16x8 pkA, pkB, pvA, pvB;
  auto pfetch = [&](int tt) {
    const int nn = tt >> 4, ss = (tt & 15) << 6;
    const long nbh2 = ((long)nn * 4 + b) * 16 + h;
    const unsigned short* kb2 = kp + nbh2 * 65536;
    const unsigned short* vb2 = vpt + nbh2 * 65536;
    pkA = *(const u16x8*)&kb2[(long)(ss + r8) * 64 + c8];
    pkB = *(const u16x8*)&kb2[(long)(ss + r8 + 32) * 64 + c8];
    pvA = *(const u16x8*)&vb2[(long)r8 * 1024 + ss + c8];
    pvB = *(const u16x8*)&vb2[(long)(r8 + 32) * 1024 + ss + c8];
  };
  pfetch(0);
  int tt = 0;

  for (int n = 0; n < 2; ++n) {
    const long nbh = ((long)n * 4 + b) * 16 + h;
    // Q B-frags (held in registers for the whole source)
    const unsigned short* qrp = qp + (nbh * 1024 + t0 + q16) * 64 + g * 8;
    const bf16x8 qf0 = __builtin_bit_cast(bf16x8, *(const u16x8*)&qrp[0]);
    const bf16x8 qf1 = __builtin_bit_cast(bf16x8, *(const u16x8*)&qrp[32]);
    const float* mb = &mba[n * 1024];

    for (int s0 = 0; s0 < 1024; s0 += 64) {
      __syncthreads();  // prev tile consumed (covers mask staging on 1st iter)
      // write prefetched K [64 keys][64 d] and V^T [64 d][64 keys]
      *(u16x8*)&Ks[r8 * 72 + c8] = pkA;
      *(u16x8*)&Ks[(r8 + 32) * 72 + c8] = pkB;
      *(u16x8*)&Vt[r8 * 72 + c8] = pvA;
      *(u16x8*)&Vt[(r8 + 32) * 72 + c8] = pvB;
      __syncthreads();
      if (tt + 1 < 32) pfetch(tt + 1);  // latency hides under compute below

      // QK^T (swapped): S^T key-frags
      f32x4 st[4] = {};
#pragma unroll
      for (int kf = 0; kf < 4; ++kf) {
        const bf16x8 ka0 = __builtin_bit_cast(
            bf16x8, *(const u16x8*)&Ks[(kf * 16 + q16) * 72 + g * 8]);
        const bf16x8 ka1 = __builtin_bit_cast(
            bf16x8, *(const u16x8*)&Ks[(kf * 16 + q16) * 72 + 32 + g * 8]);
        st[kf] = __builtin_amdgcn_mfma_f32_16x16x32_bf16(ka0, qf0, st[kf], 0, 0, 0);
        st[kf] = __builtin_amdgcn_mfma_f32_16x16x32_bf16(ka1, qf1, st[kf], 0, 0, 0);
      }
      // mask + row max (key = kf*16 + g*4 + r, col = qrow = q16)
      float mt = -3.0e38f;
#pragma unroll
      for (int kf = 0; kf < 4; ++kf) {
        const f32x4 mv = *(const f32x4*)&mb[s0 + kf * 16 + g * 4];
#pragma unroll
        for (int r = 0; r < 4; ++r) {
          st[kf][r] += mv[r];
          mt = fmaxf(mt, st[kf][r]);
        }
      }
      mt = fmaxf(mt, __shfl_xor(mt, 16, 64));
      mt = fmaxf(mt, __shfl_xor(mt, 32, 64));
      const float mnew = fmaxf(m, mt);
      const float corr = __expf(m - mnew);
      float ps = 0.0f;
#pragma unroll
      for (int kf = 0; kf < 4; ++kf)
#pragma unroll
        for (int r = 0; r < 4; ++r) {
          st[kf][r] = __expf(st[kf][r] - mnew);
          ps += st[kf][r];
        }
      ps += __shfl_xor(ps, 16, 64);
      ps += __shfl_xor(ps, 32, 64);
      ls = ls * corr + ps;
      m = mnew;
#pragma unroll
      for (int df = 0; df < 4; ++df)
#pragma unroll
        for (int r = 0; r < 4; ++r) o[df][r] *= corr;
      // P -> bf16 -> per-wave LDS (row q16, keys kf*16 + g*4 .. +3)
#pragma unroll
      for (int kf = 0; kf < 4; ++kf) {
        u16x4 pp = {f2bf(st[kf][0]), f2bf(st[kf][1]), f2bf(st[kf][2]),
                    f2bf(st[kf][3])};
        *(u16x4*)&pw[kf * 16 + g * 4] = pp;
      }
      // PV: O^T += V^T · P^T  (k-dim 64 keys = 2 chunks)
      const bf16x8 pb0 = __builtin_bit_cast(bf16x8, *(const u16x8*)&pw[g * 8]);
      const bf16x8 pb1 = __builtin_bit_cast(bf16x8, *(const u16x8*)&pw[32 + g * 8]);
#pragma unroll
      for (int df = 0; df < 4; ++df) {
        const bf16x8 va0 = __builtin_bit_cast(
            bf16x8, *(const u16x8*)&Vt[(df * 16 + q16) * 72 + g * 8]);
        const bf16x8 va1 = __builtin_bit_cast(
            bf16x8, *(const u16x8*)&Vt[(df * 16 + q16) * 72 + 32 + g * 8]);
        o[df] = __builtin_amdgcn_mfma_f32_16x16x32_bf16(va0, pb0, o[df], 0, 0, 0);
        o[df] = __builtin_amdgcn_mfma_f32_16x16x32_bf16(va1, pb1, o[df], 0, 0, 0);
      }
      ++tt;
    }
  }

  // epilogue: O[qrow][d], normalize; ao row = qrow*4 + b, col = h*64 + d
  const float inv = 1.0f / ls;
  unsigned short* orow = ao + ((long)(t0 + q16) * 4 + b) * 1024 + h * 64 + g * 4;
#pragma unroll
  for (int df = 0; df < 4; ++df) {
    u16x4 ov = {f2bf(o[df][0] * inv), f2bf(o[df][1] * inv),
                f2bf(o[df][2] * inv), f2bf(o[df][3] * inv)};
    *(u16x4*)&orow[df * 16] = ov;
  }
}

// ---------------------------------------------------------------------------
extern "C" void kernel_launch(void* const* d_in, const int* in_sizes, int n_in,
                              void* d_out, int out_size, void* d_ws, size_t ws_size,
                              hipStream_t stream) {
  const float* query = (const float*)d_in[0];
  const float* keys = (const float*)d_in[1];
  const int* masks = (const int*)d_in[2];
  const float* bq = (const float*)d_in[4];
  const float* bk = (const float*)d_in[6];
  const float* bv = (const float*)d_in[8];
  const float* bo = (const float*)d_in[10];

  unsigned short* ws = (unsigned short*)d_ws;  // 94 MB used
  const dim3 blk(256);

  cvt_all<<<dim3(512, 6), blk, 0, stream>>>(query, keys, (const float*)d_in[3],
                                            (const float*)d_in[5],
                                            (const float*)d_in[7],
                                            (const float*)d_in[9], ws);
  proj_fused<<<dim3(32, 8, 6), blk, 0, stream>>>(ws, bq, bk, bv);
  attn_mfma<<<dim3(16, 16, 4), blk, 0, stream>>>(
      ws + OFF_QP, ws + OFF_KP, ws + OFF_VP, masks, ws + OFF_AO);
  gemm_out<<<dim3(32, 8, 1), blk, 0, stream>>>(ws, bo, (float*)d_out);
}